// Round 1
// baseline (501.451 us; speedup 1.0000x reference)
//
#include <hip/hip_runtime.h>

#define HIDDEN 2048
#define NH 32
#define HD 16
#define PROJ 512
#define SEQ 2048

using f32x4    = __attribute__((ext_vector_type(4))) float;
using bf16x8   = __attribute__((ext_vector_type(8))) __bf16;
using ushort4v = __attribute__((ext_vector_type(4))) unsigned short;

__device__ __forceinline__ unsigned short f2bf(float x) {
  unsigned int u = __float_as_uint(x);
  u += 0x7FFFu + ((u >> 16) & 1u);   // RNE
  return (unsigned short)(u >> 16);
}

__device__ __forceinline__ f32x4 mfma_bf16(bf16x8 a, bf16x8 b, f32x4 c) {
  return __builtin_amdgcn_mfma_f32_16x16x32_bf16(a, b, c, 0, 0, 0);
}

// ---------------------------------------------------------------------------
// Fused QKV projection: C[4096,512] = X[4096,2048] @ W.T, W given [512,2048].
// 128x128 tile, BK=32, 4 waves each 64x64 (4x4 frags of 16x16x32).
// Epilogue scatters bf16 to [B,NH,S,D]; q gets SCALE=0.125.
// ---------------------------------------------------------------------------
__global__ __launch_bounds__(256)
void proj_kernel(const float* __restrict__ q, const float* __restrict__ k,
                 const float* __restrict__ v, const float* __restrict__ Wq,
                 const float* __restrict__ Wk, const float* __restrict__ Wv,
                 unsigned short* __restrict__ qh, unsigned short* __restrict__ kh,
                 unsigned short* __restrict__ vh) {
  const int z = blockIdx.z;
  const float* A = (z == 0) ? q : (z == 1) ? k : v;
  const float* W = (z == 0) ? Wq : (z == 1) ? Wk : Wv;
  unsigned short* out = (z == 0) ? qh : (z == 1) ? kh : vh;
  const float scale = (z == 0) ? 0.125f : 1.0f;

  const int row0 = blockIdx.y * 128;
  const int col0 = blockIdx.x * 128;
  const int K = HIDDEN;

  __shared__ unsigned short As[128 * 40];   // [row][k], pad 32->40 (16B-aligned rows)
  __shared__ unsigned short Bs[128 * 40];   // [n][k]  (B^T layout)

  const int tid = threadIdx.x;
  const int wv_ = tid >> 6;
  const int lane = tid & 63;
  const int ln = lane & 15;
  const int qd = lane >> 4;
  const int wm = wv_ >> 1, wn = wv_ & 1;

  f32x4 acc[4][4];
#pragma unroll
  for (int mi = 0; mi < 4; mi++)
#pragma unroll
    for (int ni = 0; ni < 4; ni++) acc[mi][ni] = (f32x4){0.f, 0.f, 0.f, 0.f};

  for (int k0 = 0; k0 < K; k0 += 32) {
#pragma unroll
    for (int i = 0; i < 4; i++) {
      int e = i * 256 + tid;          // 0..1023
      int r = e >> 3;                 // 8 float4 per 32-wide row
      int c = (e & 7) << 2;
      f32x4 av = *(const f32x4*)(A + (size_t)(row0 + r) * K + k0 + c);
      f32x4 wv2 = *(const f32x4*)(W + (size_t)(col0 + r) * K + k0 + c);
      ushort4v a4, b4;
#pragma unroll
      for (int j = 0; j < 4; j++) { a4[j] = f2bf(av[j]); b4[j] = f2bf(wv2[j]); }
      *(ushort4v*)&As[r * 40 + c] = a4;
      *(ushort4v*)&Bs[r * 40 + c] = b4;
    }
    __syncthreads();

    bf16x8 af[4], bfv[4];
#pragma unroll
    for (int mi = 0; mi < 4; mi++)
      af[mi] = *(const bf16x8*)&As[(wm * 64 + mi * 16 + ln) * 40 + qd * 8];
#pragma unroll
    for (int ni = 0; ni < 4; ni++)
      bfv[ni] = *(const bf16x8*)&Bs[(wn * 64 + ni * 16 + ln) * 40 + qd * 8];
#pragma unroll
    for (int mi = 0; mi < 4; mi++)
#pragma unroll
      for (int ni = 0; ni < 4; ni++)
        acc[mi][ni] = mfma_bf16(af[mi], bfv[ni], acc[mi][ni]);
    __syncthreads();
  }

#pragma unroll
  for (int mi = 0; mi < 4; mi++)
#pragma unroll
    for (int ni = 0; ni < 4; ni++) {
      int h = (col0 + wn * 64 + ni * 16) >> 4;     // frag spans exactly one head
#pragma unroll
      for (int r = 0; r < 4; r++) {
        int grow = row0 + wm * 64 + mi * 16 + qd * 4 + r;
        int b = grow >> 11, s = grow & 2047;
        out[((size_t)(b * NH + h) * SEQ + s) * HD + ln] = f2bf(acc[mi][ni][r] * scale);
      }
    }
}

// ---------------------------------------------------------------------------
// Flash attention: block = (128 q-rows, one (b,h)). d=16 zero-padded to K=32
// for QK^T. P goes C-layout -> LDS -> A-layout for PV. Online softmax.
// ---------------------------------------------------------------------------
__global__ __launch_bounds__(256)
void flash_kernel(const unsigned short* __restrict__ qh,
                  const unsigned short* __restrict__ kh,
                  const unsigned short* __restrict__ vh,
                  float* __restrict__ attn_out) {
  const int bh = blockIdx.y;
  const int b = bh >> 5, h = bh & 31;
  const int q0 = blockIdx.x * 128;
  const size_t hoff = (size_t)bh * SEQ * HD;
  const unsigned short* Q = qh + hoff;
  const unsigned short* Kp = kh + hoff;
  const unsigned short* Vp = vh + hoff;

  __shared__ unsigned short Qs[128 * 40];      // [q][d] padded, d16..31 zero
  __shared__ unsigned short Ks[128 * 40];      // [key][d] padded, d16..31 zero
  __shared__ unsigned short Vt[16 * 136];      // [d][key] transposed
  __shared__ unsigned short Ps[4 * 32 * 136];  // per-wave [qrow][key]

  const int tid = threadIdx.x;
  const int w = tid >> 6;
  const int lane = tid & 63;
  const int ln = lane & 15;
  const int qd = lane >> 4;

#pragma unroll
  for (int i = 0; i < 8; i++) {
    int e = i * 256 + tid;
    int r = e >> 4, d = e & 15;
    Qs[r * 40 + d] = Q[(size_t)(q0 + r) * HD + d];
    Qs[r * 40 + 16 + d] = 0;
  }

  float m_st[2][4], l_st[2][4];
  f32x4 o_acc[2];
#pragma unroll
  for (int mi = 0; mi < 2; mi++) {
#pragma unroll
    for (int r = 0; r < 4; r++) { m_st[mi][r] = -1e30f; l_st[mi][r] = 0.f; }
    o_acc[mi] = (f32x4){0.f, 0.f, 0.f, 0.f};
  }
  __syncthreads();

  for (int t = 0; t < 16; t++) {
    const int kb = t * 128;
#pragma unroll
    for (int i = 0; i < 8; i++) {
      int e = i * 256 + tid;
      int r = e >> 4, d = e & 15;
      unsigned short kv = Kp[(size_t)(kb + r) * HD + d];
      Ks[r * 40 + d] = kv;
      Ks[r * 40 + 16 + d] = 0;
      Vt[d * 136 + r] = Vp[(size_t)(kb + r) * HD + d];
    }
    __syncthreads();

    bf16x8 aq[2], bk[8], bv[4];
#pragma unroll
    for (int mi = 0; mi < 2; mi++)
      aq[mi] = *(const bf16x8*)&Qs[(w * 32 + mi * 16 + ln) * 40 + qd * 8];
#pragma unroll
    for (int ni = 0; ni < 8; ni++)
      bk[ni] = *(const bf16x8*)&Ks[(ni * 16 + ln) * 40 + qd * 8];
#pragma unroll
    for (int ks = 0; ks < 4; ks++)
      bv[ks] = *(const bf16x8*)&Vt[ln * 136 + ks * 32 + qd * 8];

    f32x4 sc[2][8];
#pragma unroll
    for (int mi = 0; mi < 2; mi++)
#pragma unroll
      for (int ni = 0; ni < 8; ni++) {
        f32x4 zz = {0.f, 0.f, 0.f, 0.f};
        sc[mi][ni] = mfma_bf16(aq[mi], bk[ni], zz);
      }

#pragma unroll
    for (int mi = 0; mi < 2; mi++) {
#pragma unroll
      for (int r = 0; r < 4; r++) {
        float mx = sc[mi][0][r];
#pragma unroll
        for (int ni = 1; ni < 8; ni++) mx = fmaxf(mx, sc[mi][ni][r]);
#pragma unroll
        for (int off = 1; off < 16; off <<= 1)
          mx = fmaxf(mx, __shfl_xor(mx, off, 64));
        float mo = m_st[mi][r];
        float mn = fmaxf(mo, mx);
        float alpha = __expf(mo - mn);
        m_st[mi][r] = mn;
        float rs = 0.f;
#pragma unroll
        for (int ni = 0; ni < 8; ni++) {
          float p = __expf(sc[mi][ni][r] - mn);
          sc[mi][ni][r] = p;
          rs += p;
        }
#pragma unroll
        for (int off = 1; off < 16; off <<= 1)
          rs += __shfl_xor(rs, off, 64);
        l_st[mi][r] = l_st[mi][r] * alpha + rs;
        o_acc[mi][r] = o_acc[mi][r] * alpha;
        int prow = w * 32 + mi * 16 + qd * 4 + r;
#pragma unroll
        for (int ni = 0; ni < 8; ni++)
          Ps[prow * 136 + ni * 16 + ln] = f2bf(sc[mi][ni][r]);
      }
    }
    __syncthreads();   // Ps flushed; all waves done with Ks/Vt (bv in regs)

#pragma unroll
    for (int ks = 0; ks < 4; ks++)
#pragma unroll
      for (int mi = 0; mi < 2; mi++) {
        bf16x8 ap = *(const bf16x8*)&Ps[(w * 32 + mi * 16 + ln) * 136 + ks * 32 + qd * 8];
        o_acc[mi] = mfma_bf16(ap, bv[ks], o_acc[mi]);
      }
  }

#pragma unroll
  for (int mi = 0; mi < 2; mi++)
#pragma unroll
    for (int r = 0; r < 4; r++) {
      float invl = 1.0f / l_st[mi][r];
      int s = q0 + w * 32 + mi * 16 + qd * 4 + r;
      attn_out[((size_t)(b * SEQ + s)) * PROJ + h * HD + ln] = o_acc[mi][r] * invl;
    }
}

// ---------------------------------------------------------------------------
// Output projection: out[4096,2048] = attn[4096,512] @ Wo.T, Wo [2048,512].
// ---------------------------------------------------------------------------
__global__ __launch_bounds__(256)
void out_kernel(const float* __restrict__ Aatt, const float* __restrict__ Wo,
                float* __restrict__ out) {
  const int row0 = blockIdx.y * 128;
  const int col0 = blockIdx.x * 128;
  const int K = PROJ;

  __shared__ unsigned short As[128 * 40];
  __shared__ unsigned short Bs[128 * 40];

  const int tid = threadIdx.x;
  const int wv_ = tid >> 6;
  const int lane = tid & 63;
  const int ln = lane & 15;
  const int qd = lane >> 4;
  const int wm = wv_ >> 1, wn = wv_ & 1;

  f32x4 acc[4][4];
#pragma unroll
  for (int mi = 0; mi < 4; mi++)
#pragma unroll
    for (int ni = 0; ni < 4; ni++) acc[mi][ni] = (f32x4){0.f, 0.f, 0.f, 0.f};

  for (int k0 = 0; k0 < K; k0 += 32) {
#pragma unroll
    for (int i = 0; i < 4; i++) {
      int e = i * 256 + tid;
      int r = e >> 3;
      int c = (e & 7) << 2;
      f32x4 av = *(const f32x4*)(Aatt + (size_t)(row0 + r) * K + k0 + c);
      f32x4 wv2 = *(const f32x4*)(Wo + (size_t)(col0 + r) * K + k0 + c);
      ushort4v a4, b4;
#pragma unroll
      for (int j = 0; j < 4; j++) { a4[j] = f2bf(av[j]); b4[j] = f2bf(wv2[j]); }
      *(ushort4v*)&As[r * 40 + c] = a4;
      *(ushort4v*)&Bs[r * 40 + c] = b4;
    }
    __syncthreads();

    bf16x8 af[4], bfv[4];
#pragma unroll
    for (int mi = 0; mi < 4; mi++)
      af[mi] = *(const bf16x8*)&As[(wm * 64 + mi * 16 + ln) * 40 + qd * 8];
#pragma unroll
    for (int ni = 0; ni < 4; ni++)
      bfv[ni] = *(const bf16x8*)&Bs[(wn * 64 + ni * 16 + ln) * 40 + qd * 8];
#pragma unroll
    for (int mi = 0; mi < 4; mi++)
#pragma unroll
      for (int ni = 0; ni < 4; ni++)
        acc[mi][ni] = mfma_bf16(af[mi], bfv[ni], acc[mi][ni]);
    __syncthreads();
  }

#pragma unroll
  for (int mi = 0; mi < 4; mi++)
#pragma unroll
    for (int ni = 0; ni < 4; ni++) {
      int gcol = col0 + wn * 64 + ni * 16 + ln;
#pragma unroll
      for (int r = 0; r < 4; r++) {
        int grow = row0 + wm * 64 + mi * 16 + qd * 4 + r;
        out[(size_t)grow * HIDDEN + gcol] = acc[mi][ni][r];
      }
    }
}

extern "C" void kernel_launch(void* const* d_in, const int* in_sizes, int n_in,
                              void* d_out, int out_size, void* d_ws, size_t ws_size,
                              hipStream_t stream) {
  const float* q  = (const float*)d_in[0];
  const float* k  = (const float*)d_in[1];
  const float* v  = (const float*)d_in[2];
  const float* Wq = (const float*)d_in[3];
  const float* Wk = (const float*)d_in[4];
  const float* Wv = (const float*)d_in[5];
  const float* Wo = (const float*)d_in[6];

  char* ws = (char*)d_ws;
  unsigned short* qh = (unsigned short*)(ws);                              // 4 MB  [B,NH,S,D] bf16
  unsigned short* kh = (unsigned short*)(ws + (size_t)4 * 1024 * 1024);    // 4 MB
  unsigned short* vh = (unsigned short*)(ws + (size_t)8 * 1024 * 1024);    // 4 MB
  float* attn        = (float*)(ws + (size_t)12 * 1024 * 1024);            // 8 MB  [B,S,PROJ] fp32

  proj_kernel<<<dim3(4, 32, 3), dim3(256), 0, stream>>>(q, k, v, Wq, Wk, Wv, qh, kh, vh);
  flash_kernel<<<dim3(16, 64), dim3(256), 0, stream>>>(qh, kh, vh, attn);
  out_kernel<<<dim3(16, 32), dim3(256), 0, stream>>>(attn, Wo, (float*)d_out);

  (void)in_sizes; (void)n_in; (void)out_size; (void)ws_size;
}

// Round 2
// 339.470 us; speedup vs baseline: 1.4772x; 1.4772x over previous
//
#include <hip/hip_runtime.h>

#define HIDDEN 2048
#define NH 32
#define HD 16
#define PROJ 512
#define SEQ 2048

using f32x4    = __attribute__((ext_vector_type(4))) float;
using bf16x8   = __attribute__((ext_vector_type(8))) __bf16;
using ushort4v = __attribute__((ext_vector_type(4))) unsigned short;

__device__ __forceinline__ unsigned short f2bf(float x) {
  unsigned int u = __float_as_uint(x);
  u += 0x7FFFu + ((u >> 16) & 1u);   // RNE
  return (unsigned short)(u >> 16);
}

__device__ __forceinline__ f32x4 mfma_bf16(bf16x8 a, bf16x8 b, f32x4 c) {
  return __builtin_amdgcn_mfma_f32_16x16x32_bf16(a, b, c, 0, 0, 0);
}

#define GLDS16(gptr, lptr)                                              \
  __builtin_amdgcn_global_load_lds(                                     \
      (const __attribute__((address_space(1))) unsigned int*)(gptr),    \
      (__attribute__((address_space(3))) unsigned int*)(lptr), 16, 0, 0)

// ---------------------------------------------------------------------------
// Fused QKV projection: C[4096,512] = X[4096,2048] @ W.T, W given [512,2048].
// q gets SCALE*log2(e) so attention softmax can run in exp2 domain.
// ---------------------------------------------------------------------------
__global__ __launch_bounds__(256)
void proj_kernel(const float* __restrict__ q, const float* __restrict__ k,
                 const float* __restrict__ v, const float* __restrict__ Wq,
                 const float* __restrict__ Wk, const float* __restrict__ Wv,
                 unsigned short* __restrict__ qh, unsigned short* __restrict__ kh,
                 unsigned short* __restrict__ vh) {
  const int z = blockIdx.z;
  const float* A = (z == 0) ? q : (z == 1) ? k : v;
  const float* W = (z == 0) ? Wq : (z == 1) ? Wk : Wv;
  unsigned short* out = (z == 0) ? qh : (z == 1) ? kh : vh;
  const float scale = (z == 0) ? (0.125f * 1.4426950408889634f) : 1.0f;

  const int row0 = blockIdx.y * 128;
  const int col0 = blockIdx.x * 128;
  const int K = HIDDEN;

  __shared__ unsigned short As[128 * 40];
  __shared__ unsigned short Bs[128 * 40];

  const int tid = threadIdx.x;
  const int wv_ = tid >> 6;
  const int lane = tid & 63;
  const int ln = lane & 15;
  const int qd = lane >> 4;
  const int wm = wv_ >> 1, wn = wv_ & 1;

  f32x4 acc[4][4];
#pragma unroll
  for (int mi = 0; mi < 4; mi++)
#pragma unroll
    for (int ni = 0; ni < 4; ni++) acc[mi][ni] = (f32x4){0.f, 0.f, 0.f, 0.f};

  for (int k0 = 0; k0 < K; k0 += 32) {
#pragma unroll
    for (int i = 0; i < 4; i++) {
      int e = i * 256 + tid;
      int r = e >> 3;
      int c = (e & 7) << 2;
      f32x4 av = *(const f32x4*)(A + (size_t)(row0 + r) * K + k0 + c);
      f32x4 wv2 = *(const f32x4*)(W + (size_t)(col0 + r) * K + k0 + c);
      ushort4v a4, b4;
#pragma unroll
      for (int j = 0; j < 4; j++) { a4[j] = f2bf(av[j]); b4[j] = f2bf(wv2[j]); }
      *(ushort4v*)&As[r * 40 + c] = a4;
      *(ushort4v*)&Bs[r * 40 + c] = b4;
    }
    __syncthreads();

    bf16x8 af[4], bfv[4];
#pragma unroll
    for (int mi = 0; mi < 4; mi++)
      af[mi] = *(const bf16x8*)&As[(wm * 64 + mi * 16 + ln) * 40 + qd * 8];
#pragma unroll
    for (int ni = 0; ni < 4; ni++)
      bfv[ni] = *(const bf16x8*)&Bs[(wn * 64 + ni * 16 + ln) * 40 + qd * 8];
#pragma unroll
    for (int mi = 0; mi < 4; mi++)
#pragma unroll
      for (int ni = 0; ni < 4; ni++)
        acc[mi][ni] = mfma_bf16(af[mi], bfv[ni], acc[mi][ni]);
    __syncthreads();
  }

#pragma unroll
  for (int mi = 0; mi < 4; mi++)
#pragma unroll
    for (int ni = 0; ni < 4; ni++) {
      int h = (col0 + wn * 64 + ni * 16) >> 4;
#pragma unroll
      for (int r = 0; r < 4; r++) {
        int grow = row0 + wm * 64 + mi * 16 + qd * 4 + r;
        int b = grow >> 11, s = grow & 2047;
        out[((size_t)(b * NH + h) * SEQ + s) * HD + ln] = f2bf(acc[mi][ni][r] * scale);
      }
    }
}

// ---------------------------------------------------------------------------
// Flash attention, transposed-score formulation.
//   S^T = K · Q^T  (A = K-tile, m=key; B = Q-tile, n=q)
//   C-layout: lane holds q = ln (col), keys = qd*4+r (row) -> in-register
//   softmax over keys, 2 shuffles per reduction.
//   O^T = V^T · P^T (A = V^T from LDS, B = P^T via per-wave LDS round trip).
// Double-buffered K/V staging; K via global_load_lds (contiguous 4KB tiles).
// ---------------------------------------------------------------------------
__global__ __launch_bounds__(256, 4)
void flash_kernel(const unsigned short* __restrict__ qh,
                  const unsigned short* __restrict__ kh,
                  const unsigned short* __restrict__ vh,
                  float* __restrict__ attn_out) {
  const int bh = blockIdx.y;
  const int b = bh >> 5, h = bh & 31;
  const int q0 = blockIdx.x * 128;
  const size_t hoff = (size_t)bh * SEQ * HD;
  const unsigned short* Qp = qh + hoff;
  const unsigned short* Kp = kh + hoff;
  const unsigned short* Vp = vh + hoff;

  __shared__ unsigned short Qs[128 * 16];                 // 4 KB, [q][d]
  __shared__ unsigned short Ks[2][128 * 16];              // 8 KB, [key][d]
  __shared__ unsigned short Vt[2][16 * 136];              // 8.5 KB, [d][key]
  __shared__ unsigned short Ps[4][32 * 40];               // 10 KB, per-wave [q][key%32]
  __shared__ __align__(16) unsigned short Zz[8];          // 16B zeros

  const int tid = threadIdx.x;
  const int w = tid >> 6;
  const int lane = tid & 63;
  const int ln = lane & 15;
  const int qd = lane >> 4;
  const bool hiq = (qd >= 2);

  if (tid < 8) Zz[tid] = 0;

  // stage Q (whole block, once) + K/V tile 0
  GLDS16(Qp + (size_t)q0 * HD + tid * 8, &Qs[tid * 8]);
  GLDS16(Kp + tid * 8, &Ks[0][tid * 8]);
  const uint4* Vg = (const uint4*)Vp;
  uint4 vv = Vg[tid];
  {
    int key = tid >> 1, dbase = (tid & 1) * 8;
    unsigned int wds[4] = {vv.x, vv.y, vv.z, vv.w};
#pragma unroll
    for (int j = 0; j < 8; j++) {
      unsigned short e = (j & 1) ? (unsigned short)(wds[j >> 1] >> 16)
                                 : (unsigned short)(wds[j >> 1] & 0xffffu);
      Vt[0][(dbase + j) * 136 + key] = e;
    }
  }
  __syncthreads();

  // persistent Q B-fragments: B[n=q=ln][k=d=qd*8+j], d>=16 -> zeros
  bf16x8 aq[2];
#pragma unroll
  for (int ni = 0; ni < 2; ni++) {
    const unsigned short* src =
        hiq ? Zz : &Qs[(w * 32 + ni * 16 + ln) * 16 + (qd & 1) * 8];
    aq[ni] = *(const bf16x8*)src;
  }

  float m_st[2] = {-1e30f, -1e30f};
  float l_st[2] = {0.f, 0.f};
  f32x4 o_acc[2] = {{0.f, 0.f, 0.f, 0.f}, {0.f, 0.f, 0.f, 0.f}};
  unsigned short* Pw = &Ps[w][0];

  for (int t = 0; t < 16; t++) {
    const int buf = t & 1;
    uint4 vnext;
    if (t < 15) {
      GLDS16(Kp + (size_t)(t + 1) * 2048 + tid * 8, &Ks[buf ^ 1][tid * 8]);
      vnext = Vg[(t + 1) * 256 + tid];
    }
    const unsigned short* Kb = &Ks[buf][0];
    const unsigned short* Vb = &Vt[buf][0];

#pragma unroll
    for (int c = 0; c < 4; c++) {
      f32x4 sc[2][2];
#pragma unroll
      for (int hf = 0; hf < 2; hf++) {
        int tile = c * 2 + hf;
        const unsigned short* asrc =
            hiq ? Zz : &Kb[(tile * 16 + ln) * 16 + (qd & 1) * 8];
        bf16x8 ak = *(const bf16x8*)asrc;
#pragma unroll
        for (int ni = 0; ni < 2; ni++)
          sc[ni][hf] = mfma_bf16(ak, aq[ni], (f32x4){0.f, 0.f, 0.f, 0.f});
      }
      bf16x8 av = *(const bf16x8*)&Vb[ln * 136 + c * 32 + qd * 8];

#pragma unroll
      for (int ni = 0; ni < 2; ni++) {
        // online softmax over this chunk's 32 keys (8 live in this lane)
        float mx = sc[ni][0][0];
#pragma unroll
        for (int r = 1; r < 4; r++) mx = fmaxf(mx, sc[ni][0][r]);
#pragma unroll
        for (int r = 0; r < 4; r++) mx = fmaxf(mx, sc[ni][1][r]);
        mx = fmaxf(mx, __shfl_xor(mx, 16, 64));
        mx = fmaxf(mx, __shfl_xor(mx, 32, 64));
        float mo = m_st[ni];
        float mn = fmaxf(mo, mx);
        float al = __builtin_amdgcn_exp2f(mo - mn);
        m_st[ni] = mn;
        float rs = 0.f;
#pragma unroll
        for (int hf = 0; hf < 2; hf++)
#pragma unroll
          for (int r = 0; r < 4; r++) {
            float e = __builtin_amdgcn_exp2f(sc[ni][hf][r] - mn);
            sc[ni][hf][r] = e;
            rs += e;
          }
        rs += __shfl_xor(rs, 16, 64);
        rs += __shfl_xor(rs, 32, 64);
        l_st[ni] = l_st[ni] * al + rs;
        o_acc[ni] *= al;

        // pack 8 probs -> 4 bf16x2 dwords (round-to-nearest via +0x8000)
        unsigned int u0 = __float_as_uint(sc[ni][0][0]) + 0x8000u;
        unsigned int u1 = __float_as_uint(sc[ni][0][1]) + 0x8000u;
        unsigned int u2 = __float_as_uint(sc[ni][0][2]) + 0x8000u;
        unsigned int u3 = __float_as_uint(sc[ni][0][3]) + 0x8000u;
        unsigned int u4 = __float_as_uint(sc[ni][1][0]) + 0x8000u;
        unsigned int u5 = __float_as_uint(sc[ni][1][1]) + 0x8000u;
        unsigned int u6 = __float_as_uint(sc[ni][1][2]) + 0x8000u;
        unsigned int u7 = __float_as_uint(sc[ni][1][3]) + 0x8000u;
        unsigned int d0 = __builtin_amdgcn_perm(u1, u0, 0x07060302u);
        unsigned int d1 = __builtin_amdgcn_perm(u3, u2, 0x07060302u);
        unsigned int d2 = __builtin_amdgcn_perm(u5, u4, 0x07060302u);
        unsigned int d3 = __builtin_amdgcn_perm(u7, u6, 0x07060302u);
        // row stride 40 ushorts = 80B (16B-aligned rows)
        *(uint2*)&Pw[(ni * 16 + ln) * 40 + qd * 4] = make_uint2(d0, d1);
        *(uint2*)&Pw[(ni * 16 + ln) * 40 + 16 + qd * 4] = make_uint2(d2, d3);
      }

      // PV: O^T += V^T(chunk) x P^T(chunk); same-wave LDS write->read (in-order)
#pragma unroll
      for (int ni = 0; ni < 2; ni++) {
        bf16x8 bp = *(const bf16x8*)&Pw[(ni * 16 + ln) * 40 + qd * 8];
        o_acc[ni] = mfma_bf16(av, bp, o_acc[ni]);
      }
    }

    if (t < 15) {
      int key = tid >> 1, dbase = (tid & 1) * 8;
      unsigned int wds[4] = {vnext.x, vnext.y, vnext.z, vnext.w};
#pragma unroll
      for (int j = 0; j < 8; j++) {
        unsigned short e = (j & 1) ? (unsigned short)(wds[j >> 1] >> 16)
                                   : (unsigned short)(wds[j >> 1] & 0xffffu);
        Vt[buf ^ 1][(dbase + j) * 136 + key] = e;
      }
    }
    __syncthreads();
  }

  // epilogue: lane holds q=ln, d=qd*4+{0..3} -> contiguous f32x4 store
#pragma unroll
  for (int ni = 0; ni < 2; ni++) {
    float invl = 1.0f / l_st[ni];
    int s = q0 + w * 32 + ni * 16 + ln;
    f32x4 res = o_acc[ni] * invl;
    *(f32x4*)&attn_out[((size_t)(b * SEQ + s)) * PROJ + h * HD + qd * 4] = res;
  }
}

// ---------------------------------------------------------------------------
// Output projection: out[4096,2048] = attn[4096,512] @ Wo.T, Wo [2048,512].
// ---------------------------------------------------------------------------
__global__ __launch_bounds__(256)
void out_kernel(const float* __restrict__ Aatt, const float* __restrict__ Wo,
                float* __restrict__ out) {
  const int row0 = blockIdx.y * 128;
  const int col0 = blockIdx.x * 128;
  const int K = PROJ;

  __shared__ unsigned short As[128 * 40];
  __shared__ unsigned short Bs[128 * 40];

  const int tid = threadIdx.x;
  const int wv_ = tid >> 6;
  const int lane = tid & 63;
  const int ln = lane & 15;
  const int qd = lane >> 4;
  const int wm = wv_ >> 1, wn = wv_ & 1;

  f32x4 acc[4][4];
#pragma unroll
  for (int mi = 0; mi < 4; mi++)
#pragma unroll
    for (int ni = 0; ni < 4; ni++) acc[mi][ni] = (f32x4){0.f, 0.f, 0.f, 0.f};

  for (int k0 = 0; k0 < K; k0 += 32) {
#pragma unroll
    for (int i = 0; i < 4; i++) {
      int e = i * 256 + tid;
      int r = e >> 3;
      int c = (e & 7) << 2;
      f32x4 av = *(const f32x4*)(Aatt + (size_t)(row0 + r) * K + k0 + c);
      f32x4 wv2 = *(const f32x4*)(Wo + (size_t)(col0 + r) * K + k0 + c);
      ushort4v a4, b4;
#pragma unroll
      for (int j = 0; j < 4; j++) { a4[j] = f2bf(av[j]); b4[j] = f2bf(wv2[j]); }
      *(ushort4v*)&As[r * 40 + c] = a4;
      *(ushort4v*)&Bs[r * 40 + c] = b4;
    }
    __syncthreads();

    bf16x8 af[4], bfv[4];
#pragma unroll
    for (int mi = 0; mi < 4; mi++)
      af[mi] = *(const bf16x8*)&As[(wm * 64 + mi * 16 + ln) * 40 + qd * 8];
#pragma unroll
    for (int ni = 0; ni < 4; ni++)
      bfv[ni] = *(const bf16x8*)&Bs[(wn * 64 + ni * 16 + ln) * 40 + qd * 8];
#pragma unroll
    for (int mi = 0; mi < 4; mi++)
#pragma unroll
      for (int ni = 0; ni < 4; ni++)
        acc[mi][ni] = mfma_bf16(af[mi], bfv[ni], acc[mi][ni]);
    __syncthreads();
  }

#pragma unroll
  for (int mi = 0; mi < 4; mi++)
#pragma unroll
    for (int ni = 0; ni < 4; ni++) {
      int gcol = col0 + wn * 64 + ni * 16 + ln;
#pragma unroll
      for (int r = 0; r < 4; r++) {
        int grow = row0 + wm * 64 + mi * 16 + qd * 4 + r;
        out[(size_t)grow * HIDDEN + gcol] = acc[mi][ni][r];
      }
    }
}

extern "C" void kernel_launch(void* const* d_in, const int* in_sizes, int n_in,
                              void* d_out, int out_size, void* d_ws, size_t ws_size,
                              hipStream_t stream) {
  const float* q  = (const float*)d_in[0];
  const float* k  = (const float*)d_in[1];
  const float* v  = (const float*)d_in[2];
  const float* Wq = (const float*)d_in[3];
  const float* Wk = (const float*)d_in[4];
  const float* Wv = (const float*)d_in[5];
  const float* Wo = (const float*)d_in[6];

  char* ws = (char*)d_ws;
  unsigned short* qh = (unsigned short*)(ws);
  unsigned short* kh = (unsigned short*)(ws + (size_t)4 * 1024 * 1024);
  unsigned short* vh = (unsigned short*)(ws + (size_t)8 * 1024 * 1024);
  float* attn        = (float*)(ws + (size_t)12 * 1024 * 1024);

  proj_kernel<<<dim3(4, 32, 3), dim3(256), 0, stream>>>(q, k, v, Wq, Wk, Wv, qh, kh, vh);
  flash_kernel<<<dim3(16, 64), dim3(256), 0, stream>>>(qh, kh, vh, attn);
  out_kernel<<<dim3(16, 32), dim3(256), 0, stream>>>(attn, Wo, (float*)d_out);

  (void)in_sizes; (void)n_in; (void)out_size; (void)ws_size;
}

// Round 3
// 329.676 us; speedup vs baseline: 1.5210x; 1.0297x over previous
//
#include <hip/hip_runtime.h>

#define HIDDEN 2048
#define NH 32
#define HD 16
#define PROJ 512
#define SEQ 2048

using f32x4    = __attribute__((ext_vector_type(4))) float;
using bf16x8   = __attribute__((ext_vector_type(8))) __bf16;

__device__ __forceinline__ unsigned short f2bf(float x) {
  unsigned int u = __float_as_uint(x);
  u += 0x7FFFu + ((u >> 16) & 1u);   // RNE
  return (unsigned short)(u >> 16);
}

__device__ __forceinline__ f32x4 mfma_bf16(bf16x8 a, bf16x8 b, f32x4 c) {
  return __builtin_amdgcn_mfma_f32_16x16x32_bf16(a, b, c, 0, 0, 0);
}

#define GLDS16(gptr, lptr)                                              \
  __builtin_amdgcn_global_load_lds(                                     \
      (const __attribute__((address_space(1))) unsigned int*)(gptr),    \
      (__attribute__((address_space(3))) unsigned int*)(lptr), 16, 0, 0)

// ---------------------------------------------------------------------------
// Weight pre-convert: fp32 -> bf16 (RNE), once. Identical values to the f2bf
// the GEMMs previously applied in-loop.
// ---------------------------------------------------------------------------
__global__ __launch_bounds__(256)
void convw_kernel(const float* __restrict__ Wq, const float* __restrict__ Wk,
                  const float* __restrict__ Wv, const float* __restrict__ Wo,
                  unsigned short* __restrict__ Wqb, unsigned short* __restrict__ Wkb,
                  unsigned short* __restrict__ Wvb, unsigned short* __restrict__ Wob) {
  const int z = blockIdx.y;
  const float* src = (z == 0) ? Wq : (z == 1) ? Wk : (z == 2) ? Wv : Wo;
  unsigned short* dst = (z == 0) ? Wqb : (z == 1) ? Wkb : (z == 2) ? Wvb : Wob;
  const size_t i = ((size_t)blockIdx.x * 256 + threadIdx.x) * 4;
  f32x4 v = *(const f32x4*)(src + i);
  uint2 p;
  p.x = f2bf(v[0]) | ((unsigned)f2bf(v[1]) << 16);
  p.y = f2bf(v[2]) | ((unsigned)f2bf(v[3]) << 16);
  *(uint2*)(dst + i) = p;
}

// ---------------------------------------------------------------------------
// QKV projection v3: C[4096,512] = X[4096,2048] @ W.T (W bf16 [512,2048]).
// 128x128 tile, 4 waves x (64x64), BK=32. A staged fp32 via global_load_lds
// with XOR swizzle (conflict-free frag reads); convert to bf16 at frag read.
// B staged bf16 via global_load_lds with ^(n&3) swizzle.
// ---------------------------------------------------------------------------
__global__ __launch_bounds__(256)
void proj_kernel(const float* __restrict__ q, const float* __restrict__ k,
                 const float* __restrict__ v,
                 const unsigned short* __restrict__ Wqb,
                 const unsigned short* __restrict__ Wkb,
                 const unsigned short* __restrict__ Wvb,
                 unsigned short* __restrict__ qh, unsigned short* __restrict__ kh,
                 unsigned short* __restrict__ vh) {
  const int z = blockIdx.z;
  const float* A = (z == 0) ? q : (z == 1) ? k : v;
  const unsigned short* Wb = (z == 0) ? Wqb : (z == 1) ? Wkb : Wvb;
  unsigned short* out = (z == 0) ? qh : (z == 1) ? kh : vh;
  const float scale = (z == 0) ? 0.18033688011112042f /* 0.125*log2(e) */ : 1.0f;

  const int row0 = blockIdx.y * 128;
  const int col0 = blockIdx.x * 128;

  __shared__ float As[128 * 32];             // 16 KB, slot-swizzled fp32
  __shared__ unsigned short Bs[128 * 32];    // 8 KB, slot-swizzled bf16

  const int tid = threadIdx.x;
  const int wv_ = tid >> 6;
  const int lane = tid & 63;
  const int ln = lane & 15;
  const int qd = lane >> 4;
  const int wm = wv_ >> 1, wn = wv_ & 1;

  f32x4 acc[4][4];
#pragma unroll
  for (int mi = 0; mi < 4; mi++)
#pragma unroll
    for (int ni = 0; ni < 4; ni++) acc[mi][ni] = (f32x4){0.f, 0.f, 0.f, 0.f};

  for (int k0 = 0; k0 < HIDDEN; k0 += 32) {
    // stage A: 128 rows x 32 fp32; slot L holds 16B group g = (L&7)^(m&7)
#pragma unroll
    for (int s = 0; s < 4; s++) {
      int L = s * 256 + tid;
      int m = L >> 3, gs = L & 7;
      int g = gs ^ (m & 7);
      GLDS16(A + (size_t)(row0 + m) * HIDDEN + k0 + g * 4, &As[L * 4]);
    }
    // stage B: 128 rows x 32 bf16; slot L holds 16B group g = (L&3)^(n&3)
#pragma unroll
    for (int s = 0; s < 2; s++) {
      int L = s * 256 + tid;
      int n = L >> 2, gs = L & 3;
      int g = gs ^ (n & 3);
      GLDS16(Wb + (size_t)(col0 + n) * HIDDEN + k0 + g * 8, &Bs[L * 8]);
    }
    __syncthreads();

    bf16x8 bfv[4];
#pragma unroll
    for (int ni = 0; ni < 4; ni++) {
      int n = wn * 64 + ni * 16 + ln;
      int slot = n * 4 + (qd ^ (n & 3));
      bfv[ni] = *(const bf16x8*)&Bs[slot * 8];
    }
    bf16x8 af[4];
#pragma unroll
    for (int mi = 0; mi < 4; mi++) {
      int m = wm * 64 + mi * 16 + ln;
      int base = m * 8, x = m & 7;
      f32x4 lo = *(const f32x4*)&As[(base + ((qd * 2) ^ x)) * 4];
      f32x4 hi = *(const f32x4*)&As[(base + ((qd * 2 + 1) ^ x)) * 4];
      union { bf16x8 vv; unsigned int u[4]; } cv;
      cv.u[0] = f2bf(lo[0]) | ((unsigned)f2bf(lo[1]) << 16);
      cv.u[1] = f2bf(lo[2]) | ((unsigned)f2bf(lo[3]) << 16);
      cv.u[2] = f2bf(hi[0]) | ((unsigned)f2bf(hi[1]) << 16);
      cv.u[3] = f2bf(hi[2]) | ((unsigned)f2bf(hi[3]) << 16);
      af[mi] = cv.vv;
    }
#pragma unroll
    for (int mi = 0; mi < 4; mi++)
#pragma unroll
      for (int ni = 0; ni < 4; ni++)
        acc[mi][ni] = mfma_bf16(af[mi], bfv[ni], acc[mi][ni]);
    __syncthreads();
  }

#pragma unroll
  for (int mi = 0; mi < 4; mi++)
#pragma unroll
    for (int ni = 0; ni < 4; ni++) {
      int h = (col0 + wn * 64 + ni * 16) >> 4;
#pragma unroll
      for (int r = 0; r < 4; r++) {
        int grow = row0 + wm * 64 + mi * 16 + qd * 4 + r;
        int b = grow >> 11, s = grow & 2047;
        out[((size_t)(b * NH + h) * SEQ + s) * HD + ln] = f2bf(acc[mi][ni][r] * scale);
      }
    }
}

// ---------------------------------------------------------------------------
// Flash attention (transposed-score). Unchanged from round 2 except the
// epilogue now writes bf16 attn (same f2bf the out-GEMM previously applied).
// ---------------------------------------------------------------------------
__global__ __launch_bounds__(256, 4)
void flash_kernel(const unsigned short* __restrict__ qh,
                  const unsigned short* __restrict__ kh,
                  const unsigned short* __restrict__ vh,
                  unsigned short* __restrict__ attnb) {
  const int bh = blockIdx.y;
  const int b = bh >> 5, h = bh & 31;
  const int q0 = blockIdx.x * 128;
  const size_t hoff = (size_t)bh * SEQ * HD;
  const unsigned short* Qp = qh + hoff;
  const unsigned short* Kp = kh + hoff;
  const unsigned short* Vp = vh + hoff;

  __shared__ unsigned short Qs[128 * 16];
  __shared__ unsigned short Ks[2][128 * 16];
  __shared__ unsigned short Vt[2][16 * 136];
  __shared__ unsigned short Ps[4][32 * 40];
  __shared__ __align__(16) unsigned short Zz[8];

  const int tid = threadIdx.x;
  const int w = tid >> 6;
  const int lane = tid & 63;
  const int ln = lane & 15;
  const int qd = lane >> 4;
  const bool hiq = (qd >= 2);

  if (tid < 8) Zz[tid] = 0;

  GLDS16(Qp + (size_t)q0 * HD + tid * 8, &Qs[tid * 8]);
  GLDS16(Kp + tid * 8, &Ks[0][tid * 8]);
  const uint4* Vg = (const uint4*)Vp;
  uint4 vv = Vg[tid];
  {
    int key = tid >> 1, dbase = (tid & 1) * 8;
    unsigned int wds[4] = {vv.x, vv.y, vv.z, vv.w};
#pragma unroll
    for (int j = 0; j < 8; j++) {
      unsigned short e = (j & 1) ? (unsigned short)(wds[j >> 1] >> 16)
                                 : (unsigned short)(wds[j >> 1] & 0xffffu);
      Vt[0][(dbase + j) * 136 + key] = e;
    }
  }
  __syncthreads();

  bf16x8 aq[2];
#pragma unroll
  for (int ni = 0; ni < 2; ni++) {
    const unsigned short* src =
        hiq ? Zz : &Qs[(w * 32 + ni * 16 + ln) * 16 + (qd & 1) * 8];
    aq[ni] = *(const bf16x8*)src;
  }

  float m_st[2] = {-1e30f, -1e30f};
  float l_st[2] = {0.f, 0.f};
  f32x4 o_acc[2] = {{0.f, 0.f, 0.f, 0.f}, {0.f, 0.f, 0.f, 0.f}};
  unsigned short* Pw = &Ps[w][0];

  for (int t = 0; t < 16; t++) {
    const int buf = t & 1;
    uint4 vnext;
    if (t < 15) {
      GLDS16(Kp + (size_t)(t + 1) * 2048 + tid * 8, &Ks[buf ^ 1][tid * 8]);
      vnext = Vg[(t + 1) * 256 + tid];
    }
    const unsigned short* Kb = &Ks[buf][0];
    const unsigned short* Vb = &Vt[buf][0];

#pragma unroll
    for (int c = 0; c < 4; c++) {
      f32x4 sc[2][2];
#pragma unroll
      for (int hf = 0; hf < 2; hf++) {
        int tile = c * 2 + hf;
        const unsigned short* asrc =
            hiq ? Zz : &Kb[(tile * 16 + ln) * 16 + (qd & 1) * 8];
        bf16x8 ak = *(const bf16x8*)asrc;
#pragma unroll
        for (int ni = 0; ni < 2; ni++)
          sc[ni][hf] = mfma_bf16(ak, aq[ni], (f32x4){0.f, 0.f, 0.f, 0.f});
      }
      bf16x8 av = *(const bf16x8*)&Vb[ln * 136 + c * 32 + qd * 8];

#pragma unroll
      for (int ni = 0; ni < 2; ni++) {
        float mx = sc[ni][0][0];
#pragma unroll
        for (int r = 1; r < 4; r++) mx = fmaxf(mx, sc[ni][0][r]);
#pragma unroll
        for (int r = 0; r < 4; r++) mx = fmaxf(mx, sc[ni][1][r]);
        mx = fmaxf(mx, __shfl_xor(mx, 16, 64));
        mx = fmaxf(mx, __shfl_xor(mx, 32, 64));
        float mo = m_st[ni];
        float mn = fmaxf(mo, mx);
        float al = __builtin_amdgcn_exp2f(mo - mn);
        m_st[ni] = mn;
        float rs = 0.f;
#pragma unroll
        for (int hf = 0; hf < 2; hf++)
#pragma unroll
          for (int r = 0; r < 4; r++) {
            float e = __builtin_amdgcn_exp2f(sc[ni][hf][r] - mn);
            sc[ni][hf][r] = e;
            rs += e;
          }
        rs += __shfl_xor(rs, 16, 64);
        rs += __shfl_xor(rs, 32, 64);
        l_st[ni] = l_st[ni] * al + rs;
        o_acc[ni] *= al;

        unsigned int u0 = __float_as_uint(sc[ni][0][0]) + 0x8000u;
        unsigned int u1 = __float_as_uint(sc[ni][0][1]) + 0x8000u;
        unsigned int u2 = __float_as_uint(sc[ni][0][2]) + 0x8000u;
        unsigned int u3 = __float_as_uint(sc[ni][0][3]) + 0x8000u;
        unsigned int u4 = __float_as_uint(sc[ni][1][0]) + 0x8000u;
        unsigned int u5 = __float_as_uint(sc[ni][1][1]) + 0x8000u;
        unsigned int u6 = __float_as_uint(sc[ni][1][2]) + 0x8000u;
        unsigned int u7 = __float_as_uint(sc[ni][1][3]) + 0x8000u;
        unsigned int d0 = __builtin_amdgcn_perm(u1, u0, 0x07060302u);
        unsigned int d1 = __builtin_amdgcn_perm(u3, u2, 0x07060302u);
        unsigned int d2 = __builtin_amdgcn_perm(u5, u4, 0x07060302u);
        unsigned int d3 = __builtin_amdgcn_perm(u7, u6, 0x07060302u);
        *(uint2*)&Pw[(ni * 16 + ln) * 40 + qd * 4] = make_uint2(d0, d1);
        *(uint2*)&Pw[(ni * 16 + ln) * 40 + 16 + qd * 4] = make_uint2(d2, d3);
      }

#pragma unroll
      for (int ni = 0; ni < 2; ni++) {
        bf16x8 bp = *(const bf16x8*)&Pw[(ni * 16 + ln) * 40 + qd * 8];
        o_acc[ni] = mfma_bf16(av, bp, o_acc[ni]);
      }
    }

    if (t < 15) {
      int key = tid >> 1, dbase = (tid & 1) * 8;
      unsigned int wds[4] = {vnext.x, vnext.y, vnext.z, vnext.w};
#pragma unroll
      for (int j = 0; j < 8; j++) {
        unsigned short e = (j & 1) ? (unsigned short)(wds[j >> 1] >> 16)
                                   : (unsigned short)(wds[j >> 1] & 0xffffu);
        Vt[buf ^ 1][(dbase + j) * 136 + key] = e;
      }
    }
    __syncthreads();
  }

#pragma unroll
  for (int ni = 0; ni < 2; ni++) {
    float invl = 1.0f / l_st[ni];
    int s = q0 + w * 32 + ni * 16 + ln;
    f32x4 res = o_acc[ni] * invl;
    uint2 o2;
    o2.x = f2bf(res[0]) | ((unsigned)f2bf(res[1]) << 16);
    o2.y = f2bf(res[2]) | ((unsigned)f2bf(res[3]) << 16);
    *(uint2*)&attnb[((size_t)(b * SEQ + s)) * PROJ + h * HD + qd * 4] = o2;
  }
}

// ---------------------------------------------------------------------------
// Output projection v3: out[4096,2048] = attnb[4096,512]bf16 @ Wob.T
// (Wob bf16 [2048,512]). All-bf16 glds staging, 128x128 tile, BK=32.
// ---------------------------------------------------------------------------
__global__ __launch_bounds__(256)
void out_kernel(const unsigned short* __restrict__ attnb,
                const unsigned short* __restrict__ Wob,
                float* __restrict__ out) {
  const int row0 = blockIdx.y * 128;
  const int col0 = blockIdx.x * 128;

  __shared__ unsigned short As[128 * 32];
  __shared__ unsigned short Bs[128 * 32];

  const int tid = threadIdx.x;
  const int wv_ = tid >> 6;
  const int lane = tid & 63;
  const int ln = lane & 15;
  const int qd = lane >> 4;
  const int wm = wv_ >> 1, wn = wv_ & 1;

  f32x4 acc[4][4];
#pragma unroll
  for (int mi = 0; mi < 4; mi++)
#pragma unroll
    for (int ni = 0; ni < 4; ni++) acc[mi][ni] = (f32x4){0.f, 0.f, 0.f, 0.f};

  for (int k0 = 0; k0 < PROJ; k0 += 32) {
#pragma unroll
    for (int s = 0; s < 2; s++) {
      int L = s * 256 + tid;
      int r = L >> 2, gs = L & 3;
      int g = gs ^ (r & 3);
      GLDS16(attnb + (size_t)(row0 + r) * PROJ + k0 + g * 8, &As[L * 8]);
      GLDS16(Wob + (size_t)(col0 + r) * PROJ + k0 + g * 8, &Bs[L * 8]);
    }
    __syncthreads();

    bf16x8 af[4], bfv[4];
#pragma unroll
    for (int mi = 0; mi < 4; mi++) {
      int m = wm * 64 + mi * 16 + ln;
      af[mi] = *(const bf16x8*)&As[(m * 4 + (qd ^ (m & 3))) * 8];
    }
#pragma unroll
    for (int ni = 0; ni < 4; ni++) {
      int n = wn * 64 + ni * 16 + ln;
      bfv[ni] = *(const bf16x8*)&Bs[(n * 4 + (qd ^ (n & 3))) * 8];
    }
#pragma unroll
    for (int mi = 0; mi < 4; mi++)
#pragma unroll
      for (int ni = 0; ni < 4; ni++)
        acc[mi][ni] = mfma_bf16(af[mi], bfv[ni], acc[mi][ni]);
    __syncthreads();
  }

#pragma unroll
  for (int mi = 0; mi < 4; mi++)
#pragma unroll
    for (int ni = 0; ni < 4; ni++) {
      int gcol = col0 + wn * 64 + ni * 16 + ln;
#pragma unroll
      for (int r = 0; r < 4; r++) {
        int grow = row0 + wm * 64 + mi * 16 + qd * 4 + r;
        out[(size_t)grow * HIDDEN + gcol] = acc[mi][ni][r];
      }
    }
}

extern "C" void kernel_launch(void* const* d_in, const int* in_sizes, int n_in,
                              void* d_out, int out_size, void* d_ws, size_t ws_size,
                              hipStream_t stream) {
  const float* q  = (const float*)d_in[0];
  const float* k  = (const float*)d_in[1];
  const float* v  = (const float*)d_in[2];
  const float* Wq = (const float*)d_in[3];
  const float* Wk = (const float*)d_in[4];
  const float* Wv = (const float*)d_in[5];
  const float* Wo = (const float*)d_in[6];

  char* ws = (char*)d_ws;
  const size_t MB = 1024 * 1024;
  unsigned short* qh    = (unsigned short*)(ws);            // 4 MB
  unsigned short* kh    = (unsigned short*)(ws + 4 * MB);   // 4 MB
  unsigned short* vh    = (unsigned short*)(ws + 8 * MB);   // 4 MB
  unsigned short* attnb = (unsigned short*)(ws + 12 * MB);  // 4 MB
  unsigned short* Wqb   = (unsigned short*)(ws + 16 * MB);  // 2 MB
  unsigned short* Wkb   = (unsigned short*)(ws + 18 * MB);  // 2 MB
  unsigned short* Wvb   = (unsigned short*)(ws + 20 * MB);  // 2 MB
  unsigned short* Wob   = (unsigned short*)(ws + 22 * MB);  // 2 MB -> 24 MB total

  convw_kernel<<<dim3(1024, 4), dim3(256), 0, stream>>>(Wq, Wk, Wv, Wo, Wqb, Wkb, Wvb, Wob);
  proj_kernel<<<dim3(4, 32, 3), dim3(256), 0, stream>>>(q, k, v, Wqb, Wkb, Wvb, qh, kh, vh);
  flash_kernel<<<dim3(16, 64), dim3(256), 0, stream>>>(qh, kh, vh, attnb);
  out_kernel<<<dim3(16, 32), dim3(256), 0, stream>>>(attnb, Wob, (float*)d_out);

  (void)in_sizes; (void)n_in; (void)out_size; (void)ws_size;
}